// Round 4
// baseline (13840.875 us; speedup 1.0000x reference)
//
#include <hip/hip_runtime.h>
#include <hip/hip_bf16.h>

using bf16x8 = __attribute__((ext_vector_type(8))) __bf16;
using short8 = __attribute__((ext_vector_type(8))) short;
using f32x4  = __attribute__((ext_vector_type(4))) float;
using f4     = __attribute__((ext_vector_type(4))) float;

constexpr int NB = 128;    // batch
constexpr int NT = 256;    // time
constexpr int NH = 1024;   // hidden
constexpr int NE = 256;    // embed
constexpr int NV = 256;    // vocab

constexpr int WHH_BYTES  = 48 * 2048;   // 98304: 48 rows x 1024 bf16
constexpr int WIH0_BYTES = 48 * 512;    // 24576: 48 rows x 256 bf16
constexpr int WIH1_BYTES = 48 * 1024;   // 49152: 48 rows x 512 bf16 (k<512)
constexpr int GH_FLOATS  = 8 * 256;     // 8 tiles of 16x16 f32
constexpr int NBLK = 256;

// 8 contiguous f32 -> bf16x8 (RNE via __float2bfloat16)
__device__ __forceinline__ bf16x8 cvt8(const float* p) {
  short8 r;
  #pragma unroll
  for (int j = 0; j < 8; ++j)
    r[j] = (short)__bfloat16_as_ushort(__float2bfloat16(p[j]));
  return __builtin_bit_cast(bf16x8, r);
}

// Per-group (64 WG) flag barrier. Each WG has its own 64B-padded flag:
// arrival = one release store (publishes this WG's h/y stores via L2 wb);
// wait = 64 lanes of wave0 poll all 64 flags with ONE vector load per round
// (parallel MLP, no serialized RMW chain); then agent acquire fence
// (invalidate) so post-barrier loads see peers' stores. Correct regardless
// of XCD placement; block remap only improves locality.
__device__ __forceinline__ void group_barrier(unsigned int* gflags, int slot,
                                              unsigned int ep) {
  __syncthreads();
  if (threadIdx.x == 0)
    __hip_atomic_store(gflags + slot * 16, ep, __ATOMIC_RELEASE,
                       __HIP_MEMORY_SCOPE_AGENT);
  if (threadIdx.x < 64) {
    const unsigned int* f = gflags + threadIdx.x * 16;
    while (__hip_atomic_load(f, __ATOMIC_RELAXED,
                             __HIP_MEMORY_SCOPE_AGENT) < ep) {
      __builtin_amdgcn_s_sleep(1);
    }
  }
  __builtin_amdgcn_fence(__ATOMIC_ACQUIRE, "agent");
  __syncthreads();
}

__global__ __launch_bounds__(256) void embcvt_kernel(const float* __restrict__ e,
                                                     __hip_bfloat16* __restrict__ o) {
  int i = blockIdx.x * 256 + threadIdx.x;   // grid 256*256 == VOCAB*EMBED
  o[i] = __float2bfloat16(e[i]);
}

// 256 WGs x 384 threads (6 waves). WG owns h'[rb*32 : rb*32+32, c0 : c0+16].
// Wave w: mt = w&1 (16-row m-tile), g = w>>1 (gate 0=r,1=z,2=n).
// Groups of 64 WGs (same rb) are closed under the h dependency -> per-group
// barriers only. blockIdx remap: rb = (b>>1)&3, cidx = (b&1)*32 + (b>>3)
// puts each group on 2 XCDs (round-robin dispatch) for L2 locality.
template<int LAYER>
__global__ __launch_bounds__(384) void gru_kernel(
    const int* __restrict__ x,
    const __hip_bfloat16* __restrict__ embb,  // pre-converted emb (layer0)
    const float* __restrict__ Wih,
    const float* __restrict__ Whh,
    const float* __restrict__ bih,
    const float* __restrict__ bhh,
    const float* __restrict__ h0,             // [128,1024] slice for this layer
    const __hip_bfloat16* __restrict__ yin,   // layer1: y0
    __hip_bfloat16* __restrict__ yout,        // layer0: y0
    __hip_bfloat16* __restrict__ hbuf,        // [2][128][1024]
    float* __restrict__ hout,                 // d_out h slice [128,1024] f32
    unsigned int* __restrict__ flags)         // [4][64][16] uints
{
  extern __shared__ char smem[];
  char* sWhh = smem;
  char* sWih = smem + WHH_BYTES;
  constexpr int WIH_B = (LAYER == 0) ? WIH0_BYTES : WIH1_BYTES;
  float* sGh   = (float*)(smem + WHH_BYTES + WIH_B);
  float* sBias = sGh + GH_FLOATS;

  const int tid  = threadIdx.x;
  const int lane = tid & 63;
  const int w    = tid >> 6;
  const int mt   = w & 1;
  const int g    = w >> 1;
  const int b    = blockIdx.x;
  const int rb   = (b >> 1) & 3;
  const int cidx = (b & 1) * 32 + (b >> 3);
  const int r0   = rb * 32;
  const int c0   = cidx * 16;
  unsigned int* gflags = flags + rb * 64 * 16;
  const int slot = cidx;
  const int l16  = lane & 15;
  const int lk8  = (lane >> 4) * 8;

  // ---- init: stage W_hh slice (rows g*1024+c0+j, gate-major) swizzled ----
  for (int it = 0; it < 16; ++it) {
    int idx = it * 384 + tid;                 // 0..6143
    int gr = idx >> 7, kc = idx & 127;
    int grow = (gr >> 4) * NH + c0 + (gr & 15);
    short8 v = __builtin_bit_cast(short8, cvt8(Whh + grow * NH + kc * 8));
    *(short8*)(sWhh + ((gr * 2048 + kc * 16) ^ ((gr & 7) << 4))) = v;
  }
  if constexpr (LAYER == 0) {
    for (int it = 0; it < 4; ++it) {
      int idx = it * 384 + tid;               // 0..1535
      int gr = idx >> 5, kc = idx & 31;
      int grow = (gr >> 4) * NH + c0 + (gr & 15);
      short8 v = __builtin_bit_cast(short8, cvt8(Wih + grow * NE + kc * 8));
      *(short8*)(sWih + ((gr * 512 + kc * 16) ^ ((gr & 7) << 4))) = v;
    }
  } else {
    for (int it = 0; it < 8; ++it) {
      int idx = it * 384 + tid;               // 0..3071  (k < 512)
      int gr = idx >> 6, kc = idx & 63;
      int grow = (gr >> 4) * NH + c0 + (gr & 15);
      short8 v = __builtin_bit_cast(short8, cvt8(Wih + grow * NH + kc * 8));
      *(short8*)(sWih + ((gr * 1024 + kc * 16) ^ ((gr & 7) << 4))) = v;
    }
  }
  // biases: r,z combined; n separate (reference: n = tanh(i_n + r*(h_n+bhh)))
  if (tid < 16)       sBias[tid] = bih[c0 + tid] + bhh[c0 + tid];
  else if (tid < 32)  { int c = NH + c0 + tid - 16;   sBias[tid] = bih[c] + bhh[c]; }
  else if (tid < 48)  { int c = 2*NH + c0 + tid - 32; sBias[tid] = bih[c]; }
  else if (tid < 64)  { int c = 2*NH + c0 + tid - 48; sBias[tid] = bhh[c]; }

  // layer1: W_ih k in [512,1024) stays in VGPR fragments (static-indexed)
  bf16x8 wreg[16];
  if constexpr (LAYER == 1) {
    #pragma unroll
    for (int kf = 0; kf < 16; ++kf) {
      int grow = g * NH + c0 + l16;
      wreg[kf] = cvt8(Wih + grow * NH + 512 + kf * 32 + lk8);
    }
  }

  // per-thread f32 h ownership (elems e=tid and e=tid+384 of the 32x16 chunk)
  float hown[2] = {0.f, 0.f};
  #pragma unroll
  for (int ei = 0; ei < 2; ++ei) {
    int e = tid + ei * 384;
    if (e < 512) {
      int lrow = e >> 4, lcol = e & 15;
      float hv = h0[(r0 + lrow) * NH + c0 + lcol];
      hown[ei] = hv;
      hbuf[(r0 + lrow) * NH + c0 + lcol] = __float2bfloat16(hv);  // hbuf[0] init
    }
  }
  group_barrier(gflags, slot, 1u);

  // ---- time loop ----
  for (int t = 0; t < NT; ++t) {
    const __hip_bfloat16* rbuf = hbuf + (t & 1) * (NB * NH);
    __hip_bfloat16* wbuf = hbuf + ((t + 1) & 1) * (NB * NH);
    const int arow = r0 + mt * 16 + l16;

    f32x4 acc  = {0.f, 0.f, 0.f, 0.f};
    f32x4 acc2 = {0.f, 0.f, 0.f, 0.f};

    const int brow  = g * 16 + l16;
    const int bxor  = (l16 & 7) << 4;
    const int bbase = brow * 2048 + lk8 * 2;
    const __hip_bfloat16* aptr = rbuf + arow * NH + lk8;
    #pragma unroll
    for (int kk = 0; kk < 32; ++kk) {
      bf16x8 a = __builtin_bit_cast(bf16x8, *(const short8*)(aptr + kk * 32));
      bf16x8 b = __builtin_bit_cast(bf16x8,
          *(const short8*)(sWhh + ((bbase + kk * 64) ^ bxor)));
      acc = __builtin_amdgcn_mfma_f32_16x16x32_bf16(a, b, acc, 0, 0, 0);
    }

    if constexpr (LAYER == 0) {
      int xid = x[arow * NT + t];
      const __hip_bfloat16* xptr = embb + xid * NE + lk8;
      const int bbase2 = brow * 512 + lk8 * 2;
      #pragma unroll
      for (int kk = 0; kk < 8; ++kk) {
        bf16x8 a = __builtin_bit_cast(bf16x8, *(const short8*)(xptr + kk * 32));
        bf16x8 b = __builtin_bit_cast(bf16x8,
            *(const short8*)(sWih + ((bbase2 + kk * 64) ^ bxor)));
        if (g == 2) acc2 = __builtin_amdgcn_mfma_f32_16x16x32_bf16(a, b, acc2, 0, 0, 0);
        else        acc  = __builtin_amdgcn_mfma_f32_16x16x32_bf16(a, b, acc,  0, 0, 0);
      }
    } else {
      const __hip_bfloat16* yptr = yin + (arow * NT + t) * NH + lk8;
      const int bbase2 = brow * 1024 + lk8 * 2;
      #pragma unroll
      for (int kk = 0; kk < 16; ++kk) {
        bf16x8 a = __builtin_bit_cast(bf16x8, *(const short8*)(yptr + kk * 32));
        bf16x8 b = __builtin_bit_cast(bf16x8,
            *(const short8*)(sWih + ((bbase2 + kk * 64) ^ bxor)));
        if (g == 2) acc2 = __builtin_amdgcn_mfma_f32_16x16x32_bf16(a, b, acc2, 0, 0, 0);
        else        acc  = __builtin_amdgcn_mfma_f32_16x16x32_bf16(a, b, acc,  0, 0, 0);
      }
      #pragma unroll
      for (int kf = 0; kf < 16; ++kf) {
        bf16x8 a = __builtin_bit_cast(bf16x8, *(const short8*)(yptr + 512 + kf * 32));
        if (g == 2) acc2 = __builtin_amdgcn_mfma_f32_16x16x32_bf16(a, wreg[kf], acc2, 0, 0, 0);
        else        acc  = __builtin_amdgcn_mfma_f32_16x16x32_bf16(a, wreg[kf], acc,  0, 0, 0);
      }
    }

    // C/D layout (m89): col = lane&15, row = (lane>>4)*4 + j
    {
      float* p = sGh + (g * 2 + mt) * 256 + (lane >> 4) * 64 + l16;
      p[0] = acc[0]; p[16] = acc[1]; p[32] = acc[2]; p[48] = acc[3];
      if (g == 2) {
        float* q = sGh + (6 + mt) * 256 + (lane >> 4) * 64 + l16;
        q[0] = acc2[0]; q[16] = acc2[1]; q[32] = acc2[2]; q[48] = acc2[3];
      }
    }
    __syncthreads();

    // elementwise gates (f32), h kept in registers
    #pragma unroll
    for (int ei = 0; ei < 2; ++ei) {
      int e = tid + ei * 384;
      if (e < 512) {
        int lrow = e >> 4, lcol = e & 15;
        int m2 = lrow >> 4, tr = lrow & 15;
        float ghr = sGh[(0 + m2) * 256 + tr * 16 + lcol];
        float ghz = sGh[(2 + m2) * 256 + tr * 16 + lcol];
        float ghn = sGh[(4 + m2) * 256 + tr * 16 + lcol];
        float gin = sGh[(6 + m2) * 256 + tr * 16 + lcol];
        float r = 1.f / (1.f + __expf(-(ghr + sBias[lcol])));
        float z = 1.f / (1.f + __expf(-(ghz + sBias[16 + lcol])));
        float npre = (gin + sBias[32 + lcol]) + r * (ghn + sBias[48 + lcol]);
        float n = 2.f / (1.f + __expf(-2.f * npre)) - 1.f;   // tanh, inf-safe
        float hn = (1.f - z) * n + z * hown[ei];
        hown[ei] = hn;
        __hip_bfloat16 hb = __float2bfloat16(hn);
        wbuf[(r0 + lrow) * NH + c0 + lcol] = hb;
        if constexpr (LAYER == 0)
          yout[((r0 + lrow) * NT + t) * NH + c0 + lcol] = hb;
      }
    }
    group_barrier(gflags, slot, (unsigned int)(t + 2));
  }

  #pragma unroll
  for (int ei = 0; ei < 2; ++ei) {
    int e = tid + ei * 384;
    if (e < 512) {
      int lrow = e >> 4, lcol = e & 15;
      hout[(r0 + lrow) * NH + c0 + lcol] = hown[ei];   // f32 output
    }
  }
}

__global__ __launch_bounds__(256) void logits_kernel(
    const __hip_bfloat16* __restrict__ h1,   // hbuf[0] after layer1
    const float* __restrict__ fcW,
    const float* __restrict__ fcb,
    float* __restrict__ out)
{
  __shared__ float hrow[NH];
  int b = blockIdx.x, v = threadIdx.x;
  for (int i = v; i < NH; i += 256) hrow[i] = __bfloat162float(h1[b * NH + i]);
  __syncthreads();
  float acc = fcb[v];
  for (int k = 0; k < NH; k += 4) {
    f4 wv = *(const f4*)(fcW + v * NH + k);
    #pragma unroll
    for (int j = 0; j < 4; ++j) acc += wv[j] * hrow[k + j];
  }
  out[b * NV + v] = acc;
}

extern "C" void kernel_launch(void* const* d_in, const int* in_sizes, int n_in,
                              void* d_out, int out_size, void* d_ws, size_t ws_size,
                              hipStream_t stream) {
  const int*   x    = (const int*)d_in[0];
  const float* h0   = (const float*)d_in[1];
  const float* emb  = (const float*)d_in[2];
  const float* Wih0 = (const float*)d_in[3];
  const float* Whh0 = (const float*)d_in[4];
  const float* bih0 = (const float*)d_in[5];
  const float* bhh0 = (const float*)d_in[6];
  const float* Wih1 = (const float*)d_in[7];
  const float* Whh1 = (const float*)d_in[8];
  const float* bih1 = (const float*)d_in[9];
  const float* bhh1 = (const float*)d_in[10];
  const float* fcW  = (const float*)d_in[11];
  const float* fcb  = (const float*)d_in[12];
  float* out = (float*)d_out;

  // ws: y0 [128,256,1024]bf16 | hbuf [2][128][1024]bf16 | embb | flags0 | flags1
  char* ws = (char*)d_ws;
  size_t off = 0;
  __hip_bfloat16* y0   = (__hip_bfloat16*)ws;            off += (size_t)NB * NT * NH * 2;
  __hip_bfloat16* hbuf = (__hip_bfloat16*)(ws + off);    off += (size_t)2 * NB * NH * 2;
  __hip_bfloat16* embb = (__hip_bfloat16*)(ws + off);    off += (size_t)NV * NE * 2;
  unsigned int*  flags0 = (unsigned int*)(ws + off);     off += 4 * 64 * 16 * 4;
  unsigned int*  flags1 = (unsigned int*)(ws + off);     off += 4 * 64 * 16 * 4;

  (void)hipMemsetAsync(flags0, 0, 2 * 4 * 64 * 16 * 4, stream);
  embcvt_kernel<<<dim3(NV * NE / 256), dim3(256), 0, stream>>>(emb, embb);

  constexpr int lds0 = WHH_BYTES + WIH0_BYTES + GH_FLOATS * 4 + 64 * 4;  // 131328
  constexpr int lds1 = WHH_BYTES + WIH1_BYTES + GH_FLOATS * 4 + 64 * 4;  // 155904
  (void)hipFuncSetAttribute(reinterpret_cast<const void*>(gru_kernel<0>),
                            hipFuncAttributeMaxDynamicSharedMemorySize, lds0);
  (void)hipFuncSetAttribute(reinterpret_cast<const void*>(gru_kernel<1>),
                            hipFuncAttributeMaxDynamicSharedMemorySize, lds1);

  gru_kernel<0><<<dim3(NBLK), dim3(384), lds0, stream>>>(
      x, embb, Wih0, Whh0, bih0, bhh0, h0, y0, y0, hbuf, out + 32768, flags0);
  gru_kernel<1><<<dim3(NBLK), dim3(384), lds1, stream>>>(
      x, embb, Wih1, Whh1, bih1, bhh1, h0 + NB * NH, y0, y0, hbuf,
      out + 32768 + NB * NH, flags1);
  logits_kernel<<<dim3(NB), dim3(256), 0, stream>>>(hbuf, fcW, fcb, out);
}

// Round 5
// 6422.353 us; speedup vs baseline: 2.1551x; 2.1551x over previous
//
#include <hip/hip_runtime.h>
#include <hip/hip_bf16.h>

using bf16x8 = __attribute__((ext_vector_type(8))) __bf16;
using short8 = __attribute__((ext_vector_type(8))) short;
using f32x4  = __attribute__((ext_vector_type(4))) float;
using f4     = __attribute__((ext_vector_type(4))) float;
using i32x4  = __attribute__((ext_vector_type(4))) int;

constexpr int NB = 128;    // batch
constexpr int NT = 256;    // time
constexpr int NH = 1024;   // hidden
constexpr int NE = 256;    // embed
constexpr int NV = 256;    // vocab

constexpr int WHH_BYTES  = 48 * 2048;   // 98304: 48 rows x 1024 bf16
constexpr int WIH0_BYTES = 48 * 512;    // 24576
constexpr int WIH1_BYTES = 48 * 1024;   // 49152 (k<512)
constexpr int GH_FLOATS  = 8 * 256;     // 8 tiles of 16x16 f32
constexpr int NBLK = 256;

// ---- cache-bypass (coherence-point) memory ops: no bulk wbl2/inv needed ----
__device__ __forceinline__ void ldg_sc(i32x4& d, const void* p) {
  asm volatile("global_load_dwordx4 %0, %1, off sc0 sc1" : "=v"(d) : "v"(p));
}
__device__ __forceinline__ void stg_sc(void* p, i32x4 v) {
  asm volatile("global_store_dwordx4 %0, %1, off sc0 sc1" :: "v"(p), "v"(v) : "memory");
}
__device__ __forceinline__ void vm0_fence() {
  asm volatile("s_waitcnt vmcnt(0)" ::: "memory");
}
__device__ __forceinline__ void use_dep(i32x4& d) {   // order consumer after fence
  asm volatile("" : "+v"(d));
}

// 8 contiguous f32 -> bf16x8 (RNE)
__device__ __forceinline__ bf16x8 cvt8(const float* p) {
  short8 r;
  #pragma unroll
  for (int j = 0; j < 8; ++j)
    r[j] = (short)__bfloat16_as_ushort(__float2bfloat16(p[j]));
  return __builtin_bit_cast(bf16x8, r);
}

__global__ __launch_bounds__(256) void embcvt_kernel(const float* __restrict__ e,
                                                     __hip_bfloat16* __restrict__ o) {
  int i = blockIdx.x * 256 + threadIdx.x;
  o[i] = __float2bfloat16(e[i]);
}

// 256 WGs x 384 threads. WG owns h'[rb*32:+32, c0:+16]. Groups of 64 WGs
// (same rb) exchange h via IC-resident (sc0 sc1) stores/loads + per-WG
// monotonic epoch flags. No grid barrier, no cache-wide fences.
template<int LAYER>
__global__ __launch_bounds__(384) void gru_kernel(
    const int* __restrict__ x,
    const __hip_bfloat16* __restrict__ embb,
    const float* __restrict__ Wih,
    const float* __restrict__ Whh,
    const float* __restrict__ bih,
    const float* __restrict__ bhh,
    const float* __restrict__ h0,
    const __hip_bfloat16* __restrict__ yin,
    __hip_bfloat16* __restrict__ yout,
    __hip_bfloat16* __restrict__ hbuf,        // [2][128][1024]
    float* __restrict__ hout,
    unsigned int* __restrict__ flags)         // [4][64][16] uints
{
  extern __shared__ char smem[];
  char* sWhh = smem;
  char* sWih = smem + WHH_BYTES;
  constexpr int WIH_B = (LAYER == 0) ? WIH0_BYTES : WIH1_BYTES;
  float* sGh   = (float*)(smem + WHH_BYTES + WIH_B);
  float* sBias = sGh + GH_FLOATS;
  char*  sH    = (char*)(sBias + 64);         // 32x16 bf16 h' staging (1KB)

  const int tid  = threadIdx.x;
  const int lane = tid & 63;
  const int w    = tid >> 6;
  const int mt   = w & 1;
  const int g    = w >> 1;
  const int b    = blockIdx.x;
  const int rb   = (b >> 1) & 3;
  const int cidx = (b & 1) * 32 + (b >> 3);
  const int r0   = rb * 32;
  const int c0   = cidx * 16;
  unsigned int* gflags = flags + rb * 64 * 16;
  const int slot = cidx;
  const int l16  = lane & 15;
  const int lk8  = (lane >> 4) * 8;

  // ---- stage W_hh slice swizzled ----
  for (int it = 0; it < 16; ++it) {
    int idx = it * 384 + tid;
    int gr = idx >> 7, kc = idx & 127;
    int grow = (gr >> 4) * NH + c0 + (gr & 15);
    short8 v = __builtin_bit_cast(short8, cvt8(Whh + grow * NH + kc * 8));
    *(short8*)(sWhh + ((gr * 2048 + kc * 16) ^ ((gr & 7) << 4))) = v;
  }
  if constexpr (LAYER == 0) {
    for (int it = 0; it < 4; ++it) {
      int idx = it * 384 + tid;
      int gr = idx >> 5, kc = idx & 31;
      int grow = (gr >> 4) * NH + c0 + (gr & 15);
      short8 v = __builtin_bit_cast(short8, cvt8(Wih + grow * NE + kc * 8));
      *(short8*)(sWih + ((gr * 512 + kc * 16) ^ ((gr & 7) << 4))) = v;
    }
  } else {
    for (int it = 0; it < 8; ++it) {
      int idx = it * 384 + tid;
      int gr = idx >> 6, kc = idx & 63;
      int grow = (gr >> 4) * NH + c0 + (gr & 15);
      short8 v = __builtin_bit_cast(short8, cvt8(Wih + grow * NH + kc * 8));
      *(short8*)(sWih + ((gr * 1024 + kc * 16) ^ ((gr & 7) << 4))) = v;
    }
  }
  if (tid < 16)       sBias[tid] = bih[c0 + tid] + bhh[c0 + tid];
  else if (tid < 32)  { int c = NH + c0 + tid - 16;   sBias[tid] = bih[c] + bhh[c]; }
  else if (tid < 48)  { int c = 2*NH + c0 + tid - 32; sBias[tid] = bih[c]; }
  else if (tid < 64)  { int c = 2*NH + c0 + tid - 48; sBias[tid] = bhh[c]; }

  bf16x8 wreg[16];
  if constexpr (LAYER == 1) {
    #pragma unroll
    for (int kf = 0; kf < 16; ++kf) {
      int grow = g * NH + c0 + l16;
      wreg[kf] = cvt8(Wih + grow * NH + 512 + kf * 32 + lk8);
    }
  }

  // ---- init h0 -> registers + sH -> sc-store to hbuf[0] + flag=1 ----
  float hown[2] = {0.f, 0.f};
  #pragma unroll
  for (int ei = 0; ei < 2; ++ei) {
    int e = tid + ei * 384;
    if (e < 512) {
      float hv = h0[(r0 + (e >> 4)) * NH + c0 + (e & 15)];
      hown[ei] = hv;
      ((unsigned short*)sH)[e] = __bfloat16_as_ushort(__float2bfloat16(hv));
    }
  }
  __syncthreads();
  if (tid < 64) {
    i32x4 hv = *(const i32x4*)(sH + (tid >> 1) * 32 + (tid & 1) * 16);
    stg_sc(hbuf + (r0 + (tid >> 1)) * NH + c0 + (tid & 1) * 8, hv);
    vm0_fence();
    if (tid == 0)
      __hip_atomic_store(gflags + slot * 16, 1u, __ATOMIC_RELAXED,
                         __HIP_MEMORY_SCOPE_AGENT);
  }

  // ---- time loop ----
  for (int t = 0; t < NT; ++t) {
    const __hip_bfloat16* rbuf = hbuf + (t & 1) * (NB * NH);
    __hip_bfloat16* wbuf = hbuf + ((t + 1) & 1) * (NB * NH);
    const int arow = r0 + mt * 16 + l16;
    const int brow = g * 16 + l16;
    const int bxor = (l16 & 7) << 4;

    f32x4 acc  = {0.f, 0.f, 0.f, 0.f};
    f32x4 acc2 = {0.f, 0.f, 0.f, 0.f};

    // ---- 1. input GEMM first (cached path, no cross-WG dep) ----
    if constexpr (LAYER == 0) {
      int xid = x[arow * NT + t];
      const __hip_bfloat16* xptr = embb + xid * NE + lk8;
      const int bbase2 = brow * 512 + lk8 * 2;
      #pragma unroll
      for (int kk = 0; kk < 8; ++kk) {
        bf16x8 a = __builtin_bit_cast(bf16x8, *(const short8*)(xptr + kk * 32));
        bf16x8 bb = __builtin_bit_cast(bf16x8,
            *(const short8*)(sWih + ((bbase2 + kk * 64) ^ bxor)));
        if (g == 2) acc2 = __builtin_amdgcn_mfma_f32_16x16x32_bf16(a, bb, acc2, 0, 0, 0);
        else        acc  = __builtin_amdgcn_mfma_f32_16x16x32_bf16(a, bb, acc,  0, 0, 0);
      }
    } else {
      const __hip_bfloat16* yptr = yin + (arow * NT + t) * NH + lk8;
      const int bbase2 = brow * 1024 + lk8 * 2;
      #pragma unroll
      for (int kk = 0; kk < 16; ++kk) {
        bf16x8 a = __builtin_bit_cast(bf16x8, *(const short8*)(yptr + kk * 32));
        bf16x8 bb = __builtin_bit_cast(bf16x8,
            *(const short8*)(sWih + ((bbase2 + kk * 64) ^ bxor)));
        if (g == 2) acc2 = __builtin_amdgcn_mfma_f32_16x16x32_bf16(a, bb, acc2, 0, 0, 0);
        else        acc  = __builtin_amdgcn_mfma_f32_16x16x32_bf16(a, bb, acc,  0, 0, 0);
      }
      #pragma unroll
      for (int kf = 0; kf < 16; ++kf) {
        bf16x8 a = __builtin_bit_cast(bf16x8, *(const short8*)(yptr + 512 + kf * 32));
        if (g == 2) acc2 = __builtin_amdgcn_mfma_f32_16x16x32_bf16(a, wreg[kf], acc2, 0, 0, 0);
        else        acc  = __builtin_amdgcn_mfma_f32_16x16x32_bf16(a, wreg[kf], acc,  0, 0, 0);
      }
    }

    // ---- 2. wait for all producers of h(t) ----
    {
      unsigned int ep = (unsigned int)(t + 1);
      if (tid < 64) {
        const unsigned int* f = gflags + tid * 16;
        while (__hip_atomic_load(f, __ATOMIC_RELAXED,
                                 __HIP_MEMORY_SCOPE_AGENT) < ep) {
          __builtin_amdgcn_s_sleep(1);
        }
      }
      __syncthreads();
    }

    // ---- 3. W_hh GEMM: sc-bypass A loads, 2 chunks of 16 in flight ----
    {
      const __hip_bfloat16* aptr = rbuf + arow * NH + lk8;
      const int bbase = brow * 2048 + lk8 * 2;
      i32x4 fr[16];
      #pragma unroll
      for (int half = 0; half < 2; ++half) {
        #pragma unroll
        for (int kk = 0; kk < 16; ++kk)
          ldg_sc(fr[kk], aptr + (half * 16 + kk) * 32);
        vm0_fence();
        #pragma unroll
        for (int kk = 0; kk < 16; ++kk) use_dep(fr[kk]);
        #pragma unroll
        for (int kk = 0; kk < 16; ++kk) {
          bf16x8 a = __builtin_bit_cast(bf16x8, fr[kk]);
          bf16x8 bb = __builtin_bit_cast(bf16x8,
              *(const short8*)(sWhh + ((bbase + (half * 16 + kk) * 64) ^ bxor)));
          acc = __builtin_amdgcn_mfma_f32_16x16x32_bf16(a, bb, acc, 0, 0, 0);
        }
      }
    }

    // C/D layout (m89): col = lane&15, row = (lane>>4)*4 + j
    {
      float* p = sGh + (g * 2 + mt) * 256 + (lane >> 4) * 64 + l16;
      p[0] = acc[0]; p[16] = acc[1]; p[32] = acc[2]; p[48] = acc[3];
      if (g == 2) {
        float* q = sGh + (6 + mt) * 256 + (lane >> 4) * 64 + l16;
        q[0] = acc2[0]; q[16] = acc2[1]; q[32] = acc2[2]; q[48] = acc2[3];
      }
    }
    __syncthreads();

    // ---- 4. gates (f32), h kept in registers; h' -> sH; y0 plain store ----
    #pragma unroll
    for (int ei = 0; ei < 2; ++ei) {
      int e = tid + ei * 384;
      if (e < 512) {
        int lrow = e >> 4, lcol = e & 15;
        int m2 = lrow >> 4, tr = lrow & 15;
        float ghr = sGh[(0 + m2) * 256 + tr * 16 + lcol];
        float ghz = sGh[(2 + m2) * 256 + tr * 16 + lcol];
        float ghn = sGh[(4 + m2) * 256 + tr * 16 + lcol];
        float gin = sGh[(6 + m2) * 256 + tr * 16 + lcol];
        float r = 1.f / (1.f + __expf(-(ghr + sBias[lcol])));
        float z = 1.f / (1.f + __expf(-(ghz + sBias[16 + lcol])));
        float npre = (gin + sBias[32 + lcol]) + r * (ghn + sBias[48 + lcol]);
        float n = 2.f / (1.f + __expf(-2.f * npre)) - 1.f;   // tanh, inf-safe
        float hn = (1.f - z) * n + z * hown[ei];
        hown[ei] = hn;
        __hip_bfloat16 hb = __float2bfloat16(hn);
        ((unsigned short*)sH)[e] = __bfloat16_as_ushort(hb);
        if constexpr (LAYER == 0)
          yout[((r0 + lrow) * NT + t) * NH + c0 + lcol] = hb;
      }
    }

    // ---- 5. publish h' (sc-store) + flag epoch t+2 ----
    __syncthreads();
    if (tid < 64) {
      i32x4 hv = *(const i32x4*)(sH + (tid >> 1) * 32 + (tid & 1) * 16);
      stg_sc(wbuf + (r0 + (tid >> 1)) * NH + c0 + (tid & 1) * 8, hv);
      vm0_fence();
      if (tid == 0)
        __hip_atomic_store(gflags + slot * 16, (unsigned int)(t + 2),
                           __ATOMIC_RELAXED, __HIP_MEMORY_SCOPE_AGENT);
    }
  }

  #pragma unroll
  for (int ei = 0; ei < 2; ++ei) {
    int e = tid + ei * 384;
    if (e < 512) {
      int lrow = e >> 4, lcol = e & 15;
      hout[(r0 + lrow) * NH + c0 + lcol] = hown[ei];
    }
  }
}

__global__ __launch_bounds__(256) void logits_kernel(
    const __hip_bfloat16* __restrict__ h1,
    const float* __restrict__ fcW,
    const float* __restrict__ fcb,
    float* __restrict__ out)
{
  __shared__ float hrow[NH];
  int b = blockIdx.x, v = threadIdx.x;
  for (int i = v; i < NH; i += 256) hrow[i] = __bfloat162float(h1[b * NH + i]);
  __syncthreads();
  float acc = fcb[v];
  for (int k = 0; k < NH; k += 4) {
    f4 wv = *(const f4*)(fcW + v * NH + k);
    #pragma unroll
    for (int j = 0; j < 4; ++j) acc += wv[j] * hrow[k + j];
  }
  out[b * NV + v] = acc;
}

extern "C" void kernel_launch(void* const* d_in, const int* in_sizes, int n_in,
                              void* d_out, int out_size, void* d_ws, size_t ws_size,
                              hipStream_t stream) {
  const int*   x    = (const int*)d_in[0];
  const float* h0   = (const float*)d_in[1];
  const float* emb  = (const float*)d_in[2];
  const float* Wih0 = (const float*)d_in[3];
  const float* Whh0 = (const float*)d_in[4];
  const float* bih0 = (const float*)d_in[5];
  const float* bhh0 = (const float*)d_in[6];
  const float* Wih1 = (const float*)d_in[7];
  const float* Whh1 = (const float*)d_in[8];
  const float* bih1 = (const float*)d_in[9];
  const float* bhh1 = (const float*)d_in[10];
  const float* fcW  = (const float*)d_in[11];
  const float* fcb  = (const float*)d_in[12];
  float* out = (float*)d_out;

  char* ws = (char*)d_ws;
  size_t off = 0;
  __hip_bfloat16* y0   = (__hip_bfloat16*)ws;            off += (size_t)NB * NT * NH * 2;
  __hip_bfloat16* hbuf = (__hip_bfloat16*)(ws + off);    off += (size_t)2 * NB * NH * 2;
  __hip_bfloat16* embb = (__hip_bfloat16*)(ws + off);    off += (size_t)NV * NE * 2;
  unsigned int*  flags0 = (unsigned int*)(ws + off);     off += 4 * 64 * 16 * 4;
  unsigned int*  flags1 = (unsigned int*)(ws + off);     off += 4 * 64 * 16 * 4;

  (void)hipMemsetAsync(flags0, 0, 2 * 4 * 64 * 16 * 4, stream);
  embcvt_kernel<<<dim3(NV * NE / 256), dim3(256), 0, stream>>>(emb, embb);

  constexpr int lds0 = WHH_BYTES + WIH0_BYTES + GH_FLOATS * 4 + 64 * 4 + 1024;  // 132352
  constexpr int lds1 = WHH_BYTES + WIH1_BYTES + GH_FLOATS * 4 + 64 * 4 + 1024;  // 156928
  (void)hipFuncSetAttribute(reinterpret_cast<const void*>(gru_kernel<0>),
                            hipFuncAttributeMaxDynamicSharedMemorySize, lds0);
  (void)hipFuncSetAttribute(reinterpret_cast<const void*>(gru_kernel<1>),
                            hipFuncAttributeMaxDynamicSharedMemorySize, lds1);

  gru_kernel<0><<<dim3(NBLK), dim3(384), lds0, stream>>>(
      x, embb, Wih0, Whh0, bih0, bhh0, h0, y0, y0, hbuf, out + 32768, flags0);
  gru_kernel<1><<<dim3(NBLK), dim3(384), lds1, stream>>>(
      x, embb, Wih1, Whh1, bih1, bhh1, h0 + NB * NH, y0, y0, hbuf,
      out + 32768 + NB * NH, flags1);
  logits_kernel<<<dim3(NB), dim3(256), 0, stream>>>(hbuf, fcW, fcb, out);
}